// Round 8
// baseline (273.838 us; speedup 1.0000x reference)
//
#include <hip/hip_runtime.h>
#include <hip/hip_bf16.h>
#include <cstdint>

static constexpr int BLK   = 256;
static constexpr int CAP   = 48;    // bucket slots/node; max degree for these
                                    // inputs ~35 (Poisson 12.5, N=50000).
                                    // Overflow handled exactly by k_fixup.
static constexpr int OVMAX = 1024;

typedef __attribute__((ext_vector_type(8))) short bf16x8;
typedef __attribute__((ext_vector_type(4))) float f32x4;

__device__ __forceinline__ float bf16lo(uint32_t u) { return __uint_as_float(u << 16); }
__device__ __forceinline__ float bf16hi(uint32_t u) { return __uint_as_float(u & 0xffff0000u); }
__device__ __forceinline__ unsigned short f2bf(float f) {
    __hip_bfloat16 h = __float2bfloat16(f);
    return *(unsigned short*)&h;
}

// ============================================================ PREP =========
// blocks [0, zb):   zero cnt_f | cnt_b | ovcnt (contiguous region, int4)
// blocks [zb, +8):  W -> bf16 transposed to [n][k]
__global__ __launch_bounds__(BLK) void k_prep(int* __restrict__ zbase, int ztot,
                                              const float* __restrict__ Wf,
                                              const float* __restrict__ Wb,
                                              unsigned short* __restrict__ WTf,
                                              unsigned short* __restrict__ WTb,
                                              int zb) {
    const int bid = blockIdx.x;
    if (bid < zb) {
        int base = bid * 1024 + threadIdx.x * 4;
        if (base < ztot) *(int4*)(zbase + base) = make_int4(0, 0, 0, 0);
        return;
    }
    int wb = bid - zb;                           // 0..7
    for (int idx = wb * 2048 + threadIdx.x; idx < (wb + 1) * 2048; idx += BLK) {
        int c = idx >> 7, k = idx & 127;
        WTf[c * 128 + k] = f2bf(Wf[k * 128 + c]);
        WTb[c * 128 + k] = f2bf(Wb[k * 128 + c]);
    }
}

// ============================================================ PHASE A ======
// blocks [0, gc):      count + direct bucket-adjacency write. The atomic
//                      return IS the slot: no scan, no fill, no rank arrays.
//                      1 edge/thread, full grid (max resident waves).
// blocks [gc, gc+gg):  MFMA GEMM h = bf16(x @ W) UNSCALED — reads x f32
//                      directly (no cvt pass); independent of the counts,
//                      hides under the atomic latency wall (m114 overlap).
__global__ __launch_bounds__(BLK) void k_phaseA(
        const int* __restrict__ src, const int* __restrict__ dst,
        int* __restrict__ cnt_f, int* __restrict__ cnt_b,
        int* __restrict__ adj_f, int* __restrict__ adj_b,
        int* __restrict__ ovcnt, int* __restrict__ ovlist, int ne,
        const float* __restrict__ x,
        const unsigned short* __restrict__ WTf,
        const unsigned short* __restrict__ WTb,
        unsigned short* __restrict__ h_f, unsigned short* __restrict__ h_b,
        int n, int gc) {
    const int bid = blockIdx.x;
    if (bid < gc) {
        int e = bid * BLK + threadIdx.x;
        if (e < ne) {
            int d = dst[e], s = src[e];
            int rf = atomicAdd(cnt_f + d, 1);
            if (rf < CAP) adj_f[d * CAP + rf] = s;
            else { int p = atomicAdd(ovcnt, 1); if (p < OVMAX) ovlist[p] = e * 2 + 0; }
            int rb = atomicAdd(cnt_b + s, 1);
            if (rb < CAP) adj_b[s * CAP + rb] = d;
            else { int p = atomicAdd(ovcnt, 1); if (p < OVMAX) ovlist[p] = e * 2 + 1; }
        }
        return;
    }
    // ---- MFMA GEMM (unscaled) ----
    const int wave = threadIdx.x >> 6;
    const int lane = threadIdx.x & 63;
    const int conv = wave >> 1;
    const int n0   = (wave & 1) * 64;
    const int m0   = (bid - gc) * 16;
    const int q    = lane >> 4;
    const int t16  = lane & 15;

    const unsigned short* __restrict__ WT = conv ? WTb : WTf;
    unsigned short* __restrict__ h        = conv ? h_b : h_f;

    int arow = m0 + t16; if (arow >= n) arow = n - 1;
    const float* __restrict__ xr = x + (size_t)arow * 128;
    bf16x8 a[4];
#pragma unroll
    for (int s = 0; s < 4; ++s) {
        float4 p0 = *(const float4*)(xr + s * 32 + q * 8);
        float4 p1 = *(const float4*)(xr + s * 32 + q * 8 + 4);
        bf16x8 v;
        v[0] = (short)f2bf(p0.x); v[1] = (short)f2bf(p0.y);
        v[2] = (short)f2bf(p0.z); v[3] = (short)f2bf(p0.w);
        v[4] = (short)f2bf(p1.x); v[5] = (short)f2bf(p1.y);
        v[6] = (short)f2bf(p1.z); v[7] = (short)f2bf(p1.w);
        a[s] = v;
    }

#pragma unroll
    for (int t = 0; t < 4; ++t) {
        const unsigned short* wrow = WT + (size_t)(n0 + t * 16 + t16) * 128;
        f32x4 c = {0.f, 0.f, 0.f, 0.f};
#pragma unroll
        for (int s = 0; s < 4; ++s) {
            bf16x8 b = *(const bf16x8*)(wrow + s * 32 + q * 8);
            c = __builtin_amdgcn_mfma_f32_16x16x32_bf16(a[s], b, c, 0, 0, 0);
        }
#pragma unroll
        for (int r = 0; r < 4; ++r) {
            int row = m0 + q * 4 + r;
            if (row < n)
                h[(size_t)row * 128 + n0 + t * 16 + t16] = f2bf(c[r]);
        }
    }
}

// ============================================================ gather =======
// wave per node; lane owns one bf16x2 dword of the feature row. Neighbor
// normalization dinv[nbr]=rsqrt(1+cnt[nbr]) computed batch-wide per lane,
// then shfl'd alongside the index; accumulation is fma (h unscaled).
__global__ __launch_bounds__(BLK) void k_gather(
        const int* __restrict__ cnt_f, const int* __restrict__ adj_f,
        const int* __restrict__ cnt_b, const int* __restrict__ adj_b,
        const uint32_t* __restrict__ hf, const uint32_t* __restrict__ hb,
        const float* __restrict__ bf, const float* __restrict__ bb,
        float* __restrict__ out, int n) {
    const int wave = threadIdx.x >> 6;
    const int lane = threadIdx.x & 63;
    const int node = blockIdx.x * 4 + wave;
    if (node >= n) return;

    float f0, f1, g0, g1;
    {
        int cf = cnt_f[node];
        float dvs = rsqrtf(1.0f + (float)cf);
        uint32_t u = hf[(size_t)node * 64 + lane];
        f0 = dvs * bf16lo(u); f1 = dvs * bf16hi(u);          // self-loop
        int m = min(cf, CAP);                                // single batch (CAP<=64)
        int   idx = 0; float dvv = 0.f;
        if (lane < m) {
            idx = adj_f[node * CAP + lane];
            dvv = rsqrtf(1.0f + (float)cnt_f[idx]);
        }
        int j = 0;
        for (; j + 8 <= m; j += 8) {
            int n0 = __shfl(idx, j + 0), n1 = __shfl(idx, j + 1);
            int n2 = __shfl(idx, j + 2), n3 = __shfl(idx, j + 3);
            int n4 = __shfl(idx, j + 4), n5 = __shfl(idx, j + 5);
            int n6 = __shfl(idx, j + 6), n7 = __shfl(idx, j + 7);
            float d0 = __shfl(dvv, j + 0), d1 = __shfl(dvv, j + 1);
            float d2 = __shfl(dvv, j + 2), d3 = __shfl(dvv, j + 3);
            float d4 = __shfl(dvv, j + 4), d5 = __shfl(dvv, j + 5);
            float d6 = __shfl(dvv, j + 6), d7 = __shfl(dvv, j + 7);
            uint32_t u0 = hf[(size_t)n0 * 64 + lane];
            uint32_t u1 = hf[(size_t)n1 * 64 + lane];
            uint32_t u2 = hf[(size_t)n2 * 64 + lane];
            uint32_t u3 = hf[(size_t)n3 * 64 + lane];
            uint32_t u4 = hf[(size_t)n4 * 64 + lane];
            uint32_t u5 = hf[(size_t)n5 * 64 + lane];
            uint32_t u6 = hf[(size_t)n6 * 64 + lane];
            uint32_t u7 = hf[(size_t)n7 * 64 + lane];
            f0 = fmaf(d0, bf16lo(u0), f0); f1 = fmaf(d0, bf16hi(u0), f1);
            f0 = fmaf(d1, bf16lo(u1), f0); f1 = fmaf(d1, bf16hi(u1), f1);
            f0 = fmaf(d2, bf16lo(u2), f0); f1 = fmaf(d2, bf16hi(u2), f1);
            f0 = fmaf(d3, bf16lo(u3), f0); f1 = fmaf(d3, bf16hi(u3), f1);
            f0 = fmaf(d4, bf16lo(u4), f0); f1 = fmaf(d4, bf16hi(u4), f1);
            f0 = fmaf(d5, bf16lo(u5), f0); f1 = fmaf(d5, bf16hi(u5), f1);
            f0 = fmaf(d6, bf16lo(u6), f0); f1 = fmaf(d6, bf16hi(u6), f1);
            f0 = fmaf(d7, bf16lo(u7), f0); f1 = fmaf(d7, bf16hi(u7), f1);
        }
        for (; j < m; ++j) {
            int nj = __shfl(idx, j); float dj = __shfl(dvv, j);
            uint32_t uj = hf[(size_t)nj * 64 + lane];
            f0 = fmaf(dj, bf16lo(uj), f0); f1 = fmaf(dj, bf16hi(uj), f1);
        }
        f0 *= dvs; f1 *= dvs;
    }
    {
        int cb = cnt_b[node];
        float dvs = rsqrtf(1.0f + (float)cb);
        uint32_t u = hb[(size_t)node * 64 + lane];
        g0 = dvs * bf16lo(u); g1 = dvs * bf16hi(u);
        int m = min(cb, CAP);
        int   idx = 0; float dvv = 0.f;
        if (lane < m) {
            idx = adj_b[node * CAP + lane];
            dvv = rsqrtf(1.0f + (float)cnt_b[idx]);
        }
        int j = 0;
        for (; j + 8 <= m; j += 8) {
            int n0 = __shfl(idx, j + 0), n1 = __shfl(idx, j + 1);
            int n2 = __shfl(idx, j + 2), n3 = __shfl(idx, j + 3);
            int n4 = __shfl(idx, j + 4), n5 = __shfl(idx, j + 5);
            int n6 = __shfl(idx, j + 6), n7 = __shfl(idx, j + 7);
            float d0 = __shfl(dvv, j + 0), d1 = __shfl(dvv, j + 1);
            float d2 = __shfl(dvv, j + 2), d3 = __shfl(dvv, j + 3);
            float d4 = __shfl(dvv, j + 4), d5 = __shfl(dvv, j + 5);
            float d6 = __shfl(dvv, j + 6), d7 = __shfl(dvv, j + 7);
            uint32_t u0 = hb[(size_t)n0 * 64 + lane];
            uint32_t u1 = hb[(size_t)n1 * 64 + lane];
            uint32_t u2 = hb[(size_t)n2 * 64 + lane];
            uint32_t u3 = hb[(size_t)n3 * 64 + lane];
            uint32_t u4 = hb[(size_t)n4 * 64 + lane];
            uint32_t u5 = hb[(size_t)n5 * 64 + lane];
            uint32_t u6 = hb[(size_t)n6 * 64 + lane];
            uint32_t u7 = hb[(size_t)n7 * 64 + lane];
            g0 = fmaf(d0, bf16lo(u0), g0); g1 = fmaf(d0, bf16hi(u0), g1);
            g0 = fmaf(d1, bf16lo(u1), g0); g1 = fmaf(d1, bf16hi(u1), g1);
            g0 = fmaf(d2, bf16lo(u2), g0); g1 = fmaf(d2, bf16hi(u2), g1);
            g0 = fmaf(d3, bf16lo(u3), g0); g1 = fmaf(d3, bf16hi(u3), g1);
            g0 = fmaf(d4, bf16lo(u4), g0); g1 = fmaf(d4, bf16hi(u4), g1);
            g0 = fmaf(d5, bf16lo(u5), g0); g1 = fmaf(d5, bf16hi(u5), g1);
            g0 = fmaf(d6, bf16lo(u6), g0); g1 = fmaf(d6, bf16hi(u6), g1);
            g0 = fmaf(d7, bf16lo(u7), g0); g1 = fmaf(d7, bf16hi(u7), g1);
        }
        for (; j < m; ++j) {
            int nj = __shfl(idx, j); float dj = __shfl(dvv, j);
            uint32_t uj = hb[(size_t)nj * 64 + lane];
            g0 = fmaf(dj, bf16lo(uj), g0); g1 = fmaf(dj, bf16hi(uj), g1);
        }
        g0 *= dvs; g1 *= dvs;
    }

    const float2 biasf = ((const float2*)bf)[lane];
    const float2 biasb = ((const float2*)bb)[lane];
    float v0 = f0 + g0 + biasf.x + biasb.x;
    float v1 = f1 + g1 + biasf.y + biasb.y;
    ((float2*)out)[(size_t)node * 64 + lane] =
        make_float2(fmaxf(v0, 0.0f), fmaxf(v1, 0.0f));
}

// ============================================================ fixup ========
// Exact recompute of any node whose bucket overflowed CAP (never triggers
// for these inputs; *ovcnt==0 -> immediate exit). Runs AFTER gather and
// overwrites the affected rows with the exact value.
__global__ __launch_bounds__(BLK) void k_fixup(
        const int* __restrict__ ovcnt, const int* __restrict__ ovlist,
        const int* __restrict__ src, const int* __restrict__ dst,
        const int* __restrict__ cnt_f, const int* __restrict__ cnt_b,
        const uint32_t* __restrict__ hf, const uint32_t* __restrict__ hb,
        const float* __restrict__ bf, const float* __restrict__ bb,
        float* __restrict__ out, int n, int ne) {
    int nov = *ovcnt; if (nov > OVMAX) nov = OVMAX;
    if (nov == 0) return;
    __shared__ int lst[4096];
    __shared__ int lcnt;
    const int tid = threadIdx.x;
    for (int i = blockIdx.x; i < nov; i += gridDim.x) {
        int code = ovlist[i];
        int e = code >> 1, dir = code & 1;
        int node = dir ? src[e] : dst[e];
        float acc0 = 0.f, acc1 = 0.f;     // lane tid<128 owns features (2t,2t+1)? use dword layout
        // accumulate both convs
        for (int d2 = 0; d2 < 2; ++d2) {
            const int* key = d2 ? src : dst;
            const int* val = d2 ? dst : src;
            const int* cnt = d2 ? cnt_b : cnt_f;
            const uint32_t* h = d2 ? hb : hf;
            float dvs = rsqrtf(1.0f + (float)cnt[node]);
            float s0 = 0.f, s1 = 0.f;
            if (tid < 64) {
                uint32_t u = h[(size_t)node * 64 + tid];
                s0 = dvs * bf16lo(u); s1 = dvs * bf16hi(u);
            }
            for (int start = 0; start < ne; start += 4096) {
                if (tid == 0) lcnt = 0;
                __syncthreads();
                int end = min(start + 4096, ne);
                for (int e2 = start + tid; e2 < end; e2 += BLK)
                    if (key[e2] == node) { int p = atomicAdd(&lcnt, 1); lst[p] = val[e2]; }
                __syncthreads();
                int mm = lcnt;
                if (tid < 64) {
                    for (int j = 0; j < mm; ++j) {
                        int nb = lst[j];
                        float dv = rsqrtf(1.0f + (float)cnt[nb]);
                        uint32_t u = h[(size_t)nb * 64 + tid];
                        s0 = fmaf(dv, bf16lo(u), s0);
                        s1 = fmaf(dv, bf16hi(u), s1);
                    }
                }
                __syncthreads();
            }
            if (tid < 64) { acc0 += dvs * s0; acc1 += dvs * s1; }
        }
        if (tid < 64) {
            float2 biasf = ((const float2*)bf)[tid];
            float2 biasb = ((const float2*)bb)[tid];
            float v0 = acc0 + biasf.x + biasb.x;
            float v1 = acc1 + biasf.y + biasb.y;
            ((float2*)out)[(size_t)node * 64 + tid] =
                make_float2(fmaxf(v0, 0.0f), fmaxf(v1, 0.0f));
        }
        __syncthreads();
    }
}

// ============================================================ launcher =====
extern "C" void kernel_launch(void* const* d_in, const int* in_sizes, int n_in,
                              void* d_out, int out_size, void* d_ws, size_t ws_size,
                              hipStream_t stream) {
    const float* x  = (const float*)d_in[0];
    const int*   ei = (const int*)d_in[1];
    const float* Wf = (const float*)d_in[2];
    const float* bf = (const float*)d_in[3];
    const float* Wb = (const float*)d_in[4];
    const float* bb = (const float*)d_in[5];

    const int n  = in_sizes[0] / 128;   // 50000
    const int ne = in_sizes[1] / 2;     // 625000
    const int* src = ei;
    const int* dst = ei + ne;
    float* out = (float*)d_out;

    // workspace layout (16B-aligned; n multiple of 4)
    char* w = (char*)d_ws;
    unsigned short* h_f = (unsigned short*)w;   w += (size_t)n * 128 * 2;   // 12.8 MB
    unsigned short* h_b = (unsigned short*)w;   w += (size_t)n * 128 * 2;
    int* adj_f = (int*)w;                       w += (size_t)n * CAP * 4;   // 9.6 MB
    int* adj_b = (int*)w;                       w += (size_t)n * CAP * 4;
    unsigned short* WTf = (unsigned short*)w;   w += 128 * 128 * 2;
    unsigned short* WTb = (unsigned short*)w;   w += 128 * 128 * 2;
    int* cnt_f = (int*)w;                       w += (size_t)n * 4;         // ---- zero
    int* cnt_b = (int*)w;                       w += (size_t)n * 4;         //  region
    int* ovcnt = (int*)w;                       w += 8 * 4;                 // ----
    int* ovlist = (int*)w;                      w += OVMAX * 4;

    const int ztot = 2 * n + 8;                    // ints to zero (mult of 4)
    const int zb   = (ztot + 1023) / 1024;         // 98 zero blocks
    const int gc   = (ne + BLK - 1) / BLK;         // 2442 edge blocks
    const int gg   = (n + 15) / 16;                // 3125 gemm blocks

    k_prep  <<<zb + 8, BLK, 0, stream>>>(cnt_f, ztot, Wf, Wb, WTf, WTb, zb);

    k_phaseA<<<gc + gg, BLK, 0, stream>>>(src, dst, cnt_f, cnt_b,
                                          adj_f, adj_b, ovcnt, ovlist, ne,
                                          x, WTf, WTb, h_f, h_b, n, gc);

    k_gather<<<(n + 3) / 4, BLK, 0, stream>>>(cnt_f, adj_f, cnt_b, adj_b,
                                              (const uint32_t*)h_f,
                                              (const uint32_t*)h_b,
                                              bf, bb, out, n);

    k_fixup <<<8, BLK, 0, stream>>>(ovcnt, ovlist, src, dst, cnt_f, cnt_b,
                                    (const uint32_t*)h_f, (const uint32_t*)h_b,
                                    bf, bb, out, n, ne);
}

// Round 9
// 243.877 us; speedup vs baseline: 1.1229x; 1.1229x over previous
//
#include <hip/hip_runtime.h>
#include <hip/hip_bf16.h>
#include <cstdint>

static constexpr int BLK   = 256;
static constexpr int CAP   = 40;    // bucket slots/node (max degree ~35 for
                                    // Poisson(12.5), N=50K); overflow exact-
                                    // fixed by the fixup blocks in k_gatherX.
static constexpr int OVMAX = 1024;

typedef __attribute__((ext_vector_type(8))) short bf16x8;
typedef __attribute__((ext_vector_type(4))) float f32x4;

__device__ __forceinline__ float bf16lo(uint32_t u) { return __uint_as_float(u << 16); }
__device__ __forceinline__ float bf16hi(uint32_t u) { return __uint_as_float(u & 0xffff0000u); }
__device__ __forceinline__ unsigned short f2bf(float f) {
    __hip_bfloat16 h = __float2bfloat16(f);
    return *(unsigned short*)&h;
}

// ============================================================ PREP =========
// blocks [0, zb):   zero cnt_f | cnt_b | ovcnt (contiguous, int4)
// blocks [zb, +8):  W -> bf16 transposed to [n][k]
__global__ __launch_bounds__(BLK) void k_prep(int* __restrict__ zbase, int ztot,
                                              const float* __restrict__ Wf,
                                              const float* __restrict__ Wb,
                                              unsigned short* __restrict__ WTf,
                                              unsigned short* __restrict__ WTb,
                                              int zb) {
    const int bid = blockIdx.x;
    if (bid < zb) {
        int base = bid * 1024 + threadIdx.x * 4;
        if (base < ztot) *(int4*)(zbase + base) = make_int4(0, 0, 0, 0);
        return;
    }
    int wb = bid - zb;                           // 0..7
    for (int idx = wb * 2048 + threadIdx.x; idx < (wb + 1) * 2048; idx += BLK) {
        int c = idx >> 7, k = idx & 127;
        WTf[c * 128 + k] = f2bf(Wf[k * 128 + c]);
        WTb[c * 128 + k] = f2bf(Wb[k * 128 + c]);
    }
}

// ============================================================ PHASE A ======
// blocks [0, gc):      count + rank. Atomic returns stored COALESCED into
//                      rank_[e] (round-8 lesson: never chain a scattered
//                      store onto the atomic return in the same kernel —
//                      the write-allocate churn fights the atomic fabric).
// blocks [gc, gc+gg):  MFMA GEMM h = bf16(x @ W) unscaled, straight from
//                      f32 x. Independent of counts; hides under the
//                      atomic latency wall (m114 pipe overlap).
__global__ __launch_bounds__(BLK) void k_phaseA(
        const int* __restrict__ src, const int* __restrict__ dst,
        int* __restrict__ cnt_f, int* __restrict__ cnt_b,
        int* __restrict__ rank_f, int* __restrict__ rank_b, int ne,
        const float* __restrict__ x,
        const unsigned short* __restrict__ WTf,
        const unsigned short* __restrict__ WTb,
        unsigned short* __restrict__ h_f, unsigned short* __restrict__ h_b,
        int n, int gc) {
    const int bid = blockIdx.x;
    if (bid < gc) {
        int e = bid * BLK + threadIdx.x;
        if (e < ne) {
            int d = dst[e], s = src[e];
            rank_f[e] = atomicAdd(cnt_f + d, 1);
            rank_b[e] = atomicAdd(cnt_b + s, 1);
        }
        return;
    }
    // ---- MFMA GEMM (unscaled) ----
    const int wave = threadIdx.x >> 6;
    const int lane = threadIdx.x & 63;
    const int conv = wave >> 1;
    const int n0   = (wave & 1) * 64;
    const int m0   = (bid - gc) * 16;
    const int q    = lane >> 4;
    const int t16  = lane & 15;

    const unsigned short* __restrict__ WT = conv ? WTb : WTf;
    unsigned short* __restrict__ h        = conv ? h_b : h_f;

    int arow = m0 + t16; if (arow >= n) arow = n - 1;
    const float* __restrict__ xr = x + (size_t)arow * 128;
    bf16x8 a[4];
#pragma unroll
    for (int s = 0; s < 4; ++s) {
        float4 p0 = *(const float4*)(xr + s * 32 + q * 8);
        float4 p1 = *(const float4*)(xr + s * 32 + q * 8 + 4);
        bf16x8 v;
        v[0] = (short)f2bf(p0.x); v[1] = (short)f2bf(p0.y);
        v[2] = (short)f2bf(p0.z); v[3] = (short)f2bf(p0.w);
        v[4] = (short)f2bf(p1.x); v[5] = (short)f2bf(p1.y);
        v[6] = (short)f2bf(p1.z); v[7] = (short)f2bf(p1.w);
        a[s] = v;
    }

#pragma unroll
    for (int t = 0; t < 4; ++t) {
        const unsigned short* wrow = WT + (size_t)(n0 + t * 16 + t16) * 128;
        f32x4 c = {0.f, 0.f, 0.f, 0.f};
#pragma unroll
        for (int s = 0; s < 4; ++s) {
            bf16x8 b = *(const bf16x8*)(wrow + s * 32 + q * 8);
            c = __builtin_amdgcn_mfma_f32_16x16x32_bf16(a[s], b, c, 0, 0, 0);
        }
#pragma unroll
        for (int r = 0; r < 4; ++r) {
            int row = m0 + q * 4 + r;
            if (row < n)
                h[(size_t)row * 128 + n0 + t * 16 + t16] = f2bf(c[r]);
        }
    }
}

// ============================================================ PHASE B ======
// blocks [0, gc):      bucket fill — atomic-free scattered stores using the
//                      precomputed ranks (no scan, no CSR offsets).
// blocks [gc, gc+gn):  dinv = rsqrt(1 + cnt), both directions, flat.
__global__ __launch_bounds__(BLK) void k_phaseB(
        const int* __restrict__ src, const int* __restrict__ dst,
        const int* __restrict__ rank_f, const int* __restrict__ rank_b,
        int* __restrict__ adj_f, int* __restrict__ adj_b,
        int* __restrict__ ovcnt, int* __restrict__ ovlist, int ne,
        const int* __restrict__ cnt_f, const int* __restrict__ cnt_b,
        float* __restrict__ dinv_f, float* __restrict__ dinv_b,
        int n, int gc) {
    const int bid = blockIdx.x;
    if (bid < gc) {
        int e = bid * BLK + threadIdx.x;
        if (e < ne) {
            int s = src[e], d = dst[e];
            int rf = rank_f[e];
            if (rf < CAP) adj_f[d * CAP + rf] = s;
            else { int p = atomicAdd(ovcnt, 1); if (p < OVMAX) ovlist[p] = e * 2 + 0; }
            int rb = rank_b[e];
            if (rb < CAP) adj_b[s * CAP + rb] = d;
            else { int p = atomicAdd(ovcnt, 1); if (p < OVMAX) ovlist[p] = e * 2 + 1; }
        }
        return;
    }
    int i = (bid - gc) * BLK + threadIdx.x;
    if (i < n) {
        dinv_f[i] = rsqrtf(1.0f + (float)cnt_f[i]);
        dinv_b[i] = rsqrtf(1.0f + (float)cnt_b[i]);
    }
}

// ============================================================ GATHER =======
// blocks [0, gnode):       wave per node; lane owns one bf16x2 dword.
//                          Skips nodes with an overflowed bucket (fixup
//                          blocks in this same dispatch own those rows —
//                          disjoint writers, no race).
// blocks [gnode, gnode+8): exact recompute of overflowed rows (no-op when
//                          *ovcnt == 0, the expected case).
__global__ __launch_bounds__(BLK) void k_gatherX(
        const int* __restrict__ cnt_f, const int* __restrict__ adj_f,
        const int* __restrict__ cnt_b, const int* __restrict__ adj_b,
        const float* __restrict__ dinv_f, const float* __restrict__ dinv_b,
        const uint32_t* __restrict__ hf, const uint32_t* __restrict__ hb,
        const float* __restrict__ bf, const float* __restrict__ bb,
        float* __restrict__ out, int n, int gnode,
        const int* __restrict__ ovcnt, const int* __restrict__ ovlist,
        const int* __restrict__ src, const int* __restrict__ dst, int ne) {
    const int bid = blockIdx.x;
    if (bid < gnode) {
        const int wave = threadIdx.x >> 6;
        const int lane = threadIdx.x & 63;
        const int node = bid * 4 + wave;
        if (node >= n) return;

        int cf = cnt_f[node], cb = cnt_b[node];
        if (cf > CAP || cb > CAP) return;          // fixup owns this row

        float f0, f1, g0, g1;
        {
            float dvs = dinv_f[node];
            uint32_t u = hf[(size_t)node * 64 + lane];
            f0 = dvs * bf16lo(u); f1 = dvs * bf16hi(u);
            int m = cf;
            int idx = 0; float dvv = 0.f;
            if (lane < m) {
                idx = adj_f[node * CAP + lane];
                dvv = dinv_f[idx];
            }
            int j = 0;
            for (; j + 8 <= m; j += 8) {
                int n0 = __shfl(idx, j + 0), n1 = __shfl(idx, j + 1);
                int n2 = __shfl(idx, j + 2), n3 = __shfl(idx, j + 3);
                int n4 = __shfl(idx, j + 4), n5 = __shfl(idx, j + 5);
                int n6 = __shfl(idx, j + 6), n7 = __shfl(idx, j + 7);
                float d0 = __shfl(dvv, j + 0), d1 = __shfl(dvv, j + 1);
                float d2 = __shfl(dvv, j + 2), d3 = __shfl(dvv, j + 3);
                float d4 = __shfl(dvv, j + 4), d5 = __shfl(dvv, j + 5);
                float d6 = __shfl(dvv, j + 6), d7 = __shfl(dvv, j + 7);
                uint32_t u0 = hf[(size_t)n0 * 64 + lane];
                uint32_t u1 = hf[(size_t)n1 * 64 + lane];
                uint32_t u2 = hf[(size_t)n2 * 64 + lane];
                uint32_t u3 = hf[(size_t)n3 * 64 + lane];
                uint32_t u4 = hf[(size_t)n4 * 64 + lane];
                uint32_t u5 = hf[(size_t)n5 * 64 + lane];
                uint32_t u6 = hf[(size_t)n6 * 64 + lane];
                uint32_t u7 = hf[(size_t)n7 * 64 + lane];
                f0 = fmaf(d0, bf16lo(u0), f0); f1 = fmaf(d0, bf16hi(u0), f1);
                f0 = fmaf(d1, bf16lo(u1), f0); f1 = fmaf(d1, bf16hi(u1), f1);
                f0 = fmaf(d2, bf16lo(u2), f0); f1 = fmaf(d2, bf16hi(u2), f1);
                f0 = fmaf(d3, bf16lo(u3), f0); f1 = fmaf(d3, bf16hi(u3), f1);
                f0 = fmaf(d4, bf16lo(u4), f0); f1 = fmaf(d4, bf16hi(u4), f1);
                f0 = fmaf(d5, bf16lo(u5), f0); f1 = fmaf(d5, bf16hi(u5), f1);
                f0 = fmaf(d6, bf16lo(u6), f0); f1 = fmaf(d6, bf16hi(u6), f1);
                f0 = fmaf(d7, bf16lo(u7), f0); f1 = fmaf(d7, bf16hi(u7), f1);
            }
            for (; j < m; ++j) {
                int nj = __shfl(idx, j); float dj = __shfl(dvv, j);
                uint32_t uj = hf[(size_t)nj * 64 + lane];
                f0 = fmaf(dj, bf16lo(uj), f0); f1 = fmaf(dj, bf16hi(uj), f1);
            }
            f0 *= dvs; f1 *= dvs;
        }
        {
            float dvs = dinv_b[node];
            uint32_t u = hb[(size_t)node * 64 + lane];
            g0 = dvs * bf16lo(u); g1 = dvs * bf16hi(u);
            int m = cb;
            int idx = 0; float dvv = 0.f;
            if (lane < m) {
                idx = adj_b[node * CAP + lane];
                dvv = dinv_b[idx];
            }
            int j = 0;
            for (; j + 8 <= m; j += 8) {
                int n0 = __shfl(idx, j + 0), n1 = __shfl(idx, j + 1);
                int n2 = __shfl(idx, j + 2), n3 = __shfl(idx, j + 3);
                int n4 = __shfl(idx, j + 4), n5 = __shfl(idx, j + 5);
                int n6 = __shfl(idx, j + 6), n7 = __shfl(idx, j + 7);
                float d0 = __shfl(dvv, j + 0), d1 = __shfl(dvv, j + 1);
                float d2 = __shfl(dvv, j + 2), d3 = __shfl(dvv, j + 3);
                float d4 = __shfl(dvv, j + 4), d5 = __shfl(dvv, j + 5);
                float d6 = __shfl(dvv, j + 6), d7 = __shfl(dvv, j + 7);
                uint32_t u0 = hb[(size_t)n0 * 64 + lane];
                uint32_t u1 = hb[(size_t)n1 * 64 + lane];
                uint32_t u2 = hb[(size_t)n2 * 64 + lane];
                uint32_t u3 = hb[(size_t)n3 * 64 + lane];
                uint32_t u4 = hb[(size_t)n4 * 64 + lane];
                uint32_t u5 = hb[(size_t)n5 * 64 + lane];
                uint32_t u6 = hb[(size_t)n6 * 64 + lane];
                uint32_t u7 = hb[(size_t)n7 * 64 + lane];
                g0 = fmaf(d0, bf16lo(u0), g0); g1 = fmaf(d0, bf16hi(u0), g1);
                g0 = fmaf(d1, bf16lo(u1), g0); g1 = fmaf(d1, bf16hi(u1), g1);
                g0 = fmaf(d2, bf16lo(u2), g0); g1 = fmaf(d2, bf16hi(u2), g1);
                g0 = fmaf(d3, bf16lo(u3), g0); g1 = fmaf(d3, bf16hi(u3), g1);
                g0 = fmaf(d4, bf16lo(u4), g0); g1 = fmaf(d4, bf16hi(u4), g1);
                g0 = fmaf(d5, bf16lo(u5), g0); g1 = fmaf(d5, bf16hi(u5), g1);
                g0 = fmaf(d6, bf16lo(u6), g0); g1 = fmaf(d6, bf16hi(u6), g1);
                g0 = fmaf(d7, bf16lo(u7), g0); g1 = fmaf(d7, bf16hi(u7), g1);
            }
            for (; j < m; ++j) {
                int nj = __shfl(idx, j); float dj = __shfl(dvv, j);
                uint32_t uj = hb[(size_t)nj * 64 + lane];
                g0 = fmaf(dj, bf16lo(uj), g0); g1 = fmaf(dj, bf16hi(uj), g1);
            }
            g0 *= dvs; g1 *= dvs;
        }

        const float2 biasf = ((const float2*)bf)[lane];
        const float2 biasb = ((const float2*)bb)[lane];
        float v0 = f0 + g0 + biasf.x + biasb.x;
        float v1 = f1 + g1 + biasf.y + biasb.y;
        ((float2*)out)[(size_t)node * 64 + lane] =
            make_float2(fmaxf(v0, 0.0f), fmaxf(v1, 0.0f));
        return;
    }

    // ---- fixup blocks: exact recompute of overflowed rows ----
    int nov = *ovcnt; if (nov > OVMAX) nov = OVMAX;
    if (nov == 0) return;
    __shared__ int lst[4096];
    __shared__ int lcnt;
    const int tid = threadIdx.x;
    for (int i = bid - gnode; i < nov; i += 8) {
        int code = ovlist[i];
        int e = code >> 1, dir = code & 1;
        int node = dir ? src[e] : dst[e];
        float acc0 = 0.f, acc1 = 0.f;
        for (int d2 = 0; d2 < 2; ++d2) {
            const int* key = d2 ? src : dst;
            const int* val = d2 ? dst : src;
            const float* dinv = d2 ? dinv_b : dinv_f;
            const uint32_t* h = d2 ? hb : hf;
            float dvs = dinv[node];
            float s0 = 0.f, s1 = 0.f;
            if (tid < 64) {
                uint32_t u = h[(size_t)node * 64 + tid];
                s0 = dvs * bf16lo(u); s1 = dvs * bf16hi(u);
            }
            for (int start = 0; start < ne; start += 4096) {
                if (tid == 0) lcnt = 0;
                __syncthreads();
                int end = min(start + 4096, ne);
                for (int e2 = start + tid; e2 < end; e2 += BLK)
                    if (key[e2] == node) { int p = atomicAdd(&lcnt, 1); lst[p] = val[e2]; }
                __syncthreads();
                int mm = lcnt;
                if (tid < 64) {
                    for (int j = 0; j < mm; ++j) {
                        int nb = lst[j];
                        float dv = dinv[nb];
                        uint32_t u = h[(size_t)nb * 64 + tid];
                        s0 = fmaf(dv, bf16lo(u), s0);
                        s1 = fmaf(dv, bf16hi(u), s1);
                    }
                }
                __syncthreads();
            }
            if (tid < 64) { acc0 += dvs * s0; acc1 += dvs * s1; }
        }
        if (tid < 64) {
            float2 biasf = ((const float2*)bf)[tid];
            float2 biasb = ((const float2*)bb)[tid];
            float v0 = acc0 + biasf.x + biasb.x;
            float v1 = acc1 + biasf.y + biasb.y;
            ((float2*)out)[(size_t)node * 64 + tid] =
                make_float2(fmaxf(v0, 0.0f), fmaxf(v1, 0.0f));
        }
        __syncthreads();
    }
}

// ============================================================ launcher =====
extern "C" void kernel_launch(void* const* d_in, const int* in_sizes, int n_in,
                              void* d_out, int out_size, void* d_ws, size_t ws_size,
                              hipStream_t stream) {
    const float* x  = (const float*)d_in[0];
    const int*   ei = (const int*)d_in[1];
    const float* Wf = (const float*)d_in[2];
    const float* bf = (const float*)d_in[3];
    const float* Wb = (const float*)d_in[4];
    const float* bb = (const float*)d_in[5];

    const int n  = in_sizes[0] / 128;   // 50000
    const int ne = in_sizes[1] / 2;     // 625000
    const int* src = ei;
    const int* dst = ei + ne;
    float* out = (float*)d_out;

    // workspace layout (16B-aligned; n, ne multiples of 4)  ~47.5 MB
    char* w = (char*)d_ws;
    unsigned short* h_f = (unsigned short*)w;   w += (size_t)n * 128 * 2;   // 12.8 MB
    unsigned short* h_b = (unsigned short*)w;   w += (size_t)n * 128 * 2;
    int* adj_f = (int*)w;                       w += (size_t)n * CAP * 4;   // 8 MB
    int* adj_b = (int*)w;                       w += (size_t)n * CAP * 4;
    int* rank_f = (int*)w;                      w += (size_t)ne * 4;        // 2.5 MB
    int* rank_b = (int*)w;                      w += (size_t)ne * 4;
    float* dinv_f = (float*)w;                  w += (size_t)n * 4;
    float* dinv_b = (float*)w;                  w += (size_t)n * 4;
    unsigned short* WTf = (unsigned short*)w;   w += 128 * 128 * 2;
    unsigned short* WTb = (unsigned short*)w;   w += 128 * 128 * 2;
    int* cnt_f = (int*)w;                       w += (size_t)n * 4;         // ---- zero
    int* cnt_b = (int*)w;                       w += (size_t)n * 4;         //  region
    int* ovcnt = (int*)w;                       w += 8 * 4;                 // ----
    int* ovlist = (int*)w;                      w += OVMAX * 4;

    const int ztot  = 2 * n + 8;
    const int zb    = (ztot + 1023) / 1024;        // 98
    const int gc    = (ne + BLK - 1) / BLK;        // 2442
    const int gg    = (n + 15) / 16;               // 3125
    const int gn    = (n + BLK - 1) / BLK;         // 196
    const int gnode = (n + 3) / 4;                 // 12500

    k_prep  <<<zb + 8, BLK, 0, stream>>>(cnt_f, ztot, Wf, Wb, WTf, WTb, zb);

    k_phaseA<<<gc + gg, BLK, 0, stream>>>(src, dst, cnt_f, cnt_b,
                                          rank_f, rank_b, ne,
                                          x, WTf, WTb, h_f, h_b, n, gc);

    k_phaseB<<<gc + gn, BLK, 0, stream>>>(src, dst, rank_f, rank_b,
                                          adj_f, adj_b, ovcnt, ovlist, ne,
                                          cnt_f, cnt_b, dinv_f, dinv_b, n, gc);

    k_gatherX<<<gnode + 8, BLK, 0, stream>>>(cnt_f, adj_f, cnt_b, adj_b,
                                             dinv_f, dinv_b,
                                             (const uint32_t*)h_f,
                                             (const uint32_t*)h_b,
                                             bf, bb, out, n, gnode,
                                             ovcnt, ovlist, src, dst, ne);
}

// Round 10
// 240.408 us; speedup vs baseline: 1.1391x; 1.0144x over previous
//
#include <hip/hip_runtime.h>
#include <hip/hip_bf16.h>
#include <cstdint>

static constexpr int BLK   = 256;
static constexpr int CAP   = 48;    // bucket slots/node = 192 B = 3 lines.
                                    // Max degree ~35 (Poisson 12.5, N=50K);
                                    // overflow exact-fixed by fixup blocks.
static constexpr int OVMAX = 1024;

typedef __attribute__((ext_vector_type(8))) short bf16x8;
typedef __attribute__((ext_vector_type(4))) float f32x4;

__device__ __forceinline__ float bf16lo(uint32_t u) { return __uint_as_float(u << 16); }
__device__ __forceinline__ float bf16hi(uint32_t u) { return __uint_as_float(u & 0xffff0000u); }
__device__ __forceinline__ unsigned short f2bf(float f) {
    __hip_bfloat16 h = __float2bfloat16(f);
    return *(unsigned short*)&h;
}

// ============================================================ PREP =========
// blocks [0, zb):   zero cnt_f | cnt_b | ovcnt (contiguous, int4)
// blocks [zb, +8):  W -> bf16 transposed to [n][k]
__global__ __launch_bounds__(BLK) void k_prep(int* __restrict__ zbase, int ztot,
                                              const float* __restrict__ Wf,
                                              const float* __restrict__ Wb,
                                              unsigned short* __restrict__ WTf,
                                              unsigned short* __restrict__ WTb,
                                              int zb) {
    const int bid = blockIdx.x;
    if (bid < zb) {
        int base = bid * 1024 + threadIdx.x * 4;
        if (base < ztot) *(int4*)(zbase + base) = make_int4(0, 0, 0, 0);
        return;
    }
    int wb = bid - zb;                           // 0..7
    for (int idx = wb * 2048 + threadIdx.x; idx < (wb + 1) * 2048; idx += BLK) {
        int c = idx >> 7, k = idx & 127;
        WTf[c * 128 + k] = f2bf(Wf[k * 128 + c]);
        WTb[c * 128 + k] = f2bf(Wb[k * 128 + c]);
    }
}

// ============================================================ COUNT ========
// Pure count + rank. NOTHING else in this dispatch: the 2.5M atomic-return
// stream is fabric-throughput-bound (~45 G/s, rounds 4/5/7/9) and any bulk
// read/write work merged here serializes against it (round-9 lesson).
// Rank stores are coalesced (round-8 lesson).
__global__ __launch_bounds__(BLK) void k_count(
        const int* __restrict__ src, const int* __restrict__ dst,
        int* __restrict__ cnt_f, int* __restrict__ cnt_b,
        int* __restrict__ rank_f, int* __restrict__ rank_b, int ne) {
    int e = blockIdx.x * BLK + threadIdx.x;
    if (e < ne) {
        int d = dst[e], s = src[e];
        rank_f[e] = atomicAdd(cnt_f + d, 1);
        rank_b[e] = atomicAdd(cnt_b + s, 1);
    }
}

// ============================================================ PHASE B ======
// blocks [0, gc):          bucket fill — atomic-free scattered stores via
//                          precomputed ranks (scatter-LATENCY bound, VALUs
//                          idle -> legit overlap partner for the GEMM).
// blocks [gc, gc+gg):      MFMA GEMM h = bf16(x @ W) unscaled, from f32 x.
// blocks [gc+gg, +gn):     dinv = rsqrt(1 + cnt), both directions.
__global__ __launch_bounds__(BLK) void k_phaseB(
        const int* __restrict__ src, const int* __restrict__ dst,
        const int* __restrict__ rank_f, const int* __restrict__ rank_b,
        int* __restrict__ adj_f, int* __restrict__ adj_b,
        int* __restrict__ ovcnt, int* __restrict__ ovlist, int ne,
        const float* __restrict__ x,
        const unsigned short* __restrict__ WTf,
        const unsigned short* __restrict__ WTb,
        unsigned short* __restrict__ h_f, unsigned short* __restrict__ h_b,
        const int* __restrict__ cnt_f, const int* __restrict__ cnt_b,
        float* __restrict__ dinv_f, float* __restrict__ dinv_b,
        int n, int gc, int gg) {
    const int bid = blockIdx.x;
    if (bid < gc) {
        int e = bid * BLK + threadIdx.x;
        if (e < ne) {
            int s = src[e], d = dst[e];
            int rf = rank_f[e];
            if (rf < CAP) adj_f[d * CAP + rf] = s;
            else { int p = atomicAdd(ovcnt, 1); if (p < OVMAX) ovlist[p] = e * 2 + 0; }
            int rb = rank_b[e];
            if (rb < CAP) adj_b[s * CAP + rb] = d;
            else { int p = atomicAdd(ovcnt, 1); if (p < OVMAX) ovlist[p] = e * 2 + 1; }
        }
        return;
    }
    if (bid < gc + gg) {
        // ---- MFMA GEMM (unscaled) ----
        const int wave = threadIdx.x >> 6;
        const int lane = threadIdx.x & 63;
        const int conv = wave >> 1;
        const int n0   = (wave & 1) * 64;
        const int m0   = (bid - gc) * 16;
        const int q    = lane >> 4;
        const int t16  = lane & 15;

        const unsigned short* __restrict__ WT = conv ? WTb : WTf;
        unsigned short* __restrict__ h        = conv ? h_b : h_f;

        int arow = m0 + t16; if (arow >= n) arow = n - 1;
        const float* __restrict__ xr = x + (size_t)arow * 128;
        bf16x8 a[4];
#pragma unroll
        for (int s = 0; s < 4; ++s) {
            float4 p0 = *(const float4*)(xr + s * 32 + q * 8);
            float4 p1 = *(const float4*)(xr + s * 32 + q * 8 + 4);
            bf16x8 v;
            v[0] = (short)f2bf(p0.x); v[1] = (short)f2bf(p0.y);
            v[2] = (short)f2bf(p0.z); v[3] = (short)f2bf(p0.w);
            v[4] = (short)f2bf(p1.x); v[5] = (short)f2bf(p1.y);
            v[6] = (short)f2bf(p1.z); v[7] = (short)f2bf(p1.w);
            a[s] = v;
        }
#pragma unroll
        for (int t = 0; t < 4; ++t) {
            const unsigned short* wrow = WT + (size_t)(n0 + t * 16 + t16) * 128;
            f32x4 c = {0.f, 0.f, 0.f, 0.f};
#pragma unroll
            for (int s = 0; s < 4; ++s) {
                bf16x8 b = *(const bf16x8*)(wrow + s * 32 + q * 8);
                c = __builtin_amdgcn_mfma_f32_16x16x32_bf16(a[s], b, c, 0, 0, 0);
            }
#pragma unroll
            for (int r = 0; r < 4; ++r) {
                int row = m0 + q * 4 + r;
                if (row < n)
                    h[(size_t)row * 128 + n0 + t * 16 + t16] = f2bf(c[r]);
            }
        }
        return;
    }
    int i = (bid - gc - gg) * BLK + threadIdx.x;
    if (i < n) {
        dinv_f[i] = rsqrtf(1.0f + (float)cnt_f[i]);
        dinv_b[i] = rsqrtf(1.0f + (float)cnt_b[i]);
    }
}

// ============================================================ GATHER =======
// blocks [0, gnode):       wave per node; lane owns one bf16x2 dword.
//   UNIFIED direction loop: both convs' neighbors packed into one lane-list
//   (lane < cf -> fwd nbr, lane in [cf, cf+cb) -> bwd nbr). Since
//   h_b == h_f + nwords, a neighbor is (dword offset, pre-scaled coeff
//   dvs_dir*dinv_dir[nbr]); one 8-wide MLP loop covers both directions —
//   ~half the latency rounds of two separate loops. Falls back to an exact
//   slow path if cf+cb > 64 (P ~ 1e-11).
// blocks [gnode, gnode+8): exact recompute of CAP-overflowed rows (no-op
//   when *ovcnt == 0, the expected case).
__global__ __launch_bounds__(BLK) void k_gatherX(
        const int* __restrict__ cnt_f, const int* __restrict__ adj_f,
        const int* __restrict__ cnt_b, const int* __restrict__ adj_b,
        const float* __restrict__ dinv_f, const float* __restrict__ dinv_b,
        const uint32_t* __restrict__ hf, const uint32_t* __restrict__ hb,
        const float* __restrict__ bf, const float* __restrict__ bb,
        float* __restrict__ out, int n, int gnode, int nwords,
        const int* __restrict__ ovcnt, const int* __restrict__ ovlist,
        const int* __restrict__ src, const int* __restrict__ dst, int ne) {
    const int bid = blockIdx.x;
    if (bid < gnode) {
        const int wave = threadIdx.x >> 6;
        const int lane = threadIdx.x & 63;
        const int node = bid * 4 + wave;
        if (node >= n) return;

        int cf = cnt_f[node], cb = cnt_b[node];
        if (cf > CAP || cb > CAP) return;          // fixup owns this row

        float dvsf = dinv_f[node], dvsb = dinv_b[node];
        uint32_t uf = hf[(size_t)node * 64 + lane];
        uint32_t ub = hb[(size_t)node * 64 + lane];
        float acc0 = dvsf * dvsf * bf16lo(uf) + dvsb * dvsb * bf16lo(ub);
        float acc1 = dvsf * dvsf * bf16hi(uf) + dvsb * dvsb * bf16hi(ub);

        const int mt = cf + cb;
        if (mt <= 64) {
            int ofs = 0; float sc = 0.f;
            if (lane < cf) {
                int nb = adj_f[node * CAP + lane];
                ofs = nb * 64;
                sc  = dvsf * dinv_f[nb];
            } else if (lane < mt) {
                int nb = adj_b[node * CAP + (lane - cf)];
                ofs = nwords + nb * 64;
                sc  = dvsb * dinv_b[nb];
            }
            int j = 0;
            for (; j + 8 <= mt; j += 8) {
                int   o0 = __shfl(ofs, j + 0), o1 = __shfl(ofs, j + 1);
                int   o2 = __shfl(ofs, j + 2), o3 = __shfl(ofs, j + 3);
                int   o4 = __shfl(ofs, j + 4), o5 = __shfl(ofs, j + 5);
                int   o6 = __shfl(ofs, j + 6), o7 = __shfl(ofs, j + 7);
                float s0 = __shfl(sc, j + 0), s1 = __shfl(sc, j + 1);
                float s2 = __shfl(sc, j + 2), s3 = __shfl(sc, j + 3);
                float s4 = __shfl(sc, j + 4), s5 = __shfl(sc, j + 5);
                float s6 = __shfl(sc, j + 6), s7 = __shfl(sc, j + 7);
                uint32_t u0 = hf[(size_t)(o0 + lane)];
                uint32_t u1 = hf[(size_t)(o1 + lane)];
                uint32_t u2 = hf[(size_t)(o2 + lane)];
                uint32_t u3 = hf[(size_t)(o3 + lane)];
                uint32_t u4 = hf[(size_t)(o4 + lane)];
                uint32_t u5 = hf[(size_t)(o5 + lane)];
                uint32_t u6 = hf[(size_t)(o6 + lane)];
                uint32_t u7 = hf[(size_t)(o7 + lane)];
                acc0 = fmaf(s0, bf16lo(u0), acc0); acc1 = fmaf(s0, bf16hi(u0), acc1);
                acc0 = fmaf(s1, bf16lo(u1), acc0); acc1 = fmaf(s1, bf16hi(u1), acc1);
                acc0 = fmaf(s2, bf16lo(u2), acc0); acc1 = fmaf(s2, bf16hi(u2), acc1);
                acc0 = fmaf(s3, bf16lo(u3), acc0); acc1 = fmaf(s3, bf16hi(u3), acc1);
                acc0 = fmaf(s4, bf16lo(u4), acc0); acc1 = fmaf(s4, bf16hi(u4), acc1);
                acc0 = fmaf(s5, bf16lo(u5), acc0); acc1 = fmaf(s5, bf16hi(u5), acc1);
                acc0 = fmaf(s6, bf16lo(u6), acc0); acc1 = fmaf(s6, bf16hi(u6), acc1);
                acc0 = fmaf(s7, bf16lo(u7), acc0); acc1 = fmaf(s7, bf16hi(u7), acc1);
            }
            for (; j + 4 <= mt; j += 4) {
                int   o0 = __shfl(ofs, j + 0), o1 = __shfl(ofs, j + 1);
                int   o2 = __shfl(ofs, j + 2), o3 = __shfl(ofs, j + 3);
                float s0 = __shfl(sc, j + 0), s1 = __shfl(sc, j + 1);
                float s2 = __shfl(sc, j + 2), s3 = __shfl(sc, j + 3);
                uint32_t u0 = hf[(size_t)(o0 + lane)];
                uint32_t u1 = hf[(size_t)(o1 + lane)];
                uint32_t u2 = hf[(size_t)(o2 + lane)];
                uint32_t u3 = hf[(size_t)(o3 + lane)];
                acc0 = fmaf(s0, bf16lo(u0), acc0); acc1 = fmaf(s0, bf16hi(u0), acc1);
                acc0 = fmaf(s1, bf16lo(u1), acc0); acc1 = fmaf(s1, bf16hi(u1), acc1);
                acc0 = fmaf(s2, bf16lo(u2), acc0); acc1 = fmaf(s2, bf16hi(u2), acc1);
                acc0 = fmaf(s3, bf16lo(u3), acc0); acc1 = fmaf(s3, bf16hi(u3), acc1);
            }
            for (; j < mt; ++j) {
                int oj = __shfl(ofs, j); float sj = __shfl(sc, j);
                uint32_t uj = hf[(size_t)(oj + lane)];
                acc0 = fmaf(sj, bf16lo(uj), acc0); acc1 = fmaf(sj, bf16hi(uj), acc1);
            }
        } else {
            // ultra-rare exact fallback (cf+cb > 64): per-j broadcast loads
            for (int j = 0; j < cf; ++j) {
                int nb = adj_f[node * CAP + j];
                float dj = dvsf * dinv_f[nb];
                uint32_t u = hf[(size_t)nb * 64 + lane];
                acc0 = fmaf(dj, bf16lo(u), acc0); acc1 = fmaf(dj, bf16hi(u), acc1);
            }
            for (int j = 0; j < cb; ++j) {
                int nb = adj_b[node * CAP + j];
                float dj = dvsb * dinv_b[nb];
                uint32_t u = hb[(size_t)nb * 64 + lane];
                acc0 = fmaf(dj, bf16lo(u), acc0); acc1 = fmaf(dj, bf16hi(u), acc1);
            }
        }

        const float2 biasf = ((const float2*)bf)[lane];
        const float2 biasb = ((const float2*)bb)[lane];
        float v0 = acc0 + biasf.x + biasb.x;
        float v1 = acc1 + biasf.y + biasb.y;
        ((float2*)out)[(size_t)node * 64 + lane] =
            make_float2(fmaxf(v0, 0.0f), fmaxf(v1, 0.0f));
        return;
    }

    // ---- fixup blocks: exact recompute of overflowed rows ----
    int nov = *ovcnt; if (nov > OVMAX) nov = OVMAX;
    if (nov == 0) return;
    __shared__ int lst[4096];
    __shared__ int lcnt;
    const int tid = threadIdx.x;
    for (int i = bid - gnode; i < nov; i += 8) {
        int code = ovlist[i];
        int e = code >> 1, dir = code & 1;
        int node = dir ? src[e] : dst[e];
        float acc0 = 0.f, acc1 = 0.f;
        for (int d2 = 0; d2 < 2; ++d2) {
            const int* key = d2 ? src : dst;
            const int* val = d2 ? dst : src;
            const float* dinv = d2 ? dinv_b : dinv_f;
            const uint32_t* h = d2 ? hb : hf;
            float dvs = dinv[node];
            float s0 = 0.f, s1 = 0.f;
            if (tid < 64) {
                uint32_t u = h[(size_t)node * 64 + tid];
                s0 = dvs * bf16lo(u); s1 = dvs * bf16hi(u);
            }
            for (int start = 0; start < ne; start += 4096) {
                if (tid == 0) lcnt = 0;
                __syncthreads();
                int end = min(start + 4096, ne);
                for (int e2 = start + tid; e2 < end; e2 += BLK)
                    if (key[e2] == node) { int p = atomicAdd(&lcnt, 1); lst[p] = val[e2]; }
                __syncthreads();
                int mm = lcnt;
                if (tid < 64) {
                    for (int j = 0; j < mm; ++j) {
                        int nb = lst[j];
                        float dv = dinv[nb];
                        uint32_t u = h[(size_t)nb * 64 + tid];
                        s0 = fmaf(dv, bf16lo(u), s0);
                        s1 = fmaf(dv, bf16hi(u), s1);
                    }
                }
                __syncthreads();
            }
            if (tid < 64) { acc0 += dvs * s0; acc1 += dvs * s1; }
        }
        if (tid < 64) {
            float2 biasf = ((const float2*)bf)[tid];
            float2 biasb = ((const float2*)bb)[tid];
            float v0 = acc0 + biasf.x + biasb.x;
            float v1 = acc1 + biasf.y + biasb.y;
            ((float2*)out)[(size_t)node * 64 + tid] =
                make_float2(fmaxf(v0, 0.0f), fmaxf(v1, 0.0f));
        }
        __syncthreads();
    }
}

// ============================================================ launcher =====
extern "C" void kernel_launch(void* const* d_in, const int* in_sizes, int n_in,
                              void* d_out, int out_size, void* d_ws, size_t ws_size,
                              hipStream_t stream) {
    const float* x  = (const float*)d_in[0];
    const int*   ei = (const int*)d_in[1];
    const float* Wf = (const float*)d_in[2];
    const float* bf = (const float*)d_in[3];
    const float* Wb = (const float*)d_in[4];
    const float* bb = (const float*)d_in[5];

    const int n  = in_sizes[0] / 128;   // 50000
    const int ne = in_sizes[1] / 2;     // 625000
    const int* src = ei;
    const int* dst = ei + ne;
    float* out = (float*)d_out;

    // workspace layout (16B-aligned; n, ne multiples of 4)
    // NOTE: h_f and h_b MUST be contiguous (gather uses hb = hf + n*64 dwords)
    char* w = (char*)d_ws;
    unsigned short* h_f = (unsigned short*)w;   w += (size_t)n * 128 * 2;   // 12.8 MB
    unsigned short* h_b = (unsigned short*)w;   w += (size_t)n * 128 * 2;   // 12.8 MB
    int* adj_f = (int*)w;                       w += (size_t)n * CAP * 4;   // 9.6 MB
    int* adj_b = (int*)w;                       w += (size_t)n * CAP * 4;
    int* rank_f = (int*)w;                      w += (size_t)ne * 4;        // 2.5 MB
    int* rank_b = (int*)w;                      w += (size_t)ne * 4;
    float* dinv_f = (float*)w;                  w += (size_t)n * 4;
    float* dinv_b = (float*)w;                  w += (size_t)n * 4;
    unsigned short* WTf = (unsigned short*)w;   w += 128 * 128 * 2;
    unsigned short* WTb = (unsigned short*)w;   w += 128 * 128 * 2;
    int* cnt_f = (int*)w;                       w += (size_t)n * 4;         // ---- zero
    int* cnt_b = (int*)w;                       w += (size_t)n * 4;         //  region
    int* ovcnt = (int*)w;                       w += 8 * 4;                 // ----
    int* ovlist = (int*)w;                      w += OVMAX * 4;

    const int ztot  = 2 * n + 8;
    const int zb    = (ztot + 1023) / 1024;        // 98
    const int gc    = (ne + BLK - 1) / BLK;        // 2442
    const int gg    = (n + 15) / 16;               // 3125
    const int gn    = (n + BLK - 1) / BLK;         // 196
    const int gnode = (n + 3) / 4;                 // 12500

    k_prep  <<<zb + 8, BLK, 0, stream>>>(cnt_f, ztot, Wf, Wb, WTf, WTb, zb);

    k_count <<<gc, BLK, 0, stream>>>(src, dst, cnt_f, cnt_b,
                                     rank_f, rank_b, ne);

    k_phaseB<<<gc + gg + gn, BLK, 0, stream>>>(src, dst, rank_f, rank_b,
                                               adj_f, adj_b, ovcnt, ovlist, ne,
                                               x, WTf, WTb, h_f, h_b,
                                               cnt_f, cnt_b, dinv_f, dinv_b,
                                               n, gc, gg);

    k_gatherX<<<gnode + 8, BLK, 0, stream>>>(cnt_f, adj_f, cnt_b, adj_b,
                                             dinv_f, dinv_b,
                                             (const uint32_t*)h_f,
                                             (const uint32_t*)h_b,
                                             bf, bb, out, n, gnode, n * 64,
                                             ovcnt, ovlist, src, dst, ne);
}